// Round 4
// baseline (49335.825 us; speedup 1.0000x reference)
//
#include <hip/hip_runtime.h>
#include <hip/hip_bf16.h>

// ---------------------------------------------------------------------------
// Decoder (Tacotron-style) on MI355X. Round 3: weight-stationary 256-block
// persistent kernel with device-scope step barriers.
// - block B: b = B>>2, slice s = B&3  ->  per-XCD weight slice ~930KB, L2-res
// - 7 global barriers per step (monotonic counter, agent-scope fences)
// - GRU weights repacked gate-interleaved uint4 (1 load = 3 gates x k-pair)
// ---------------------------------------------------------------------------

typedef unsigned int u32;

#ifndef __has_builtin
#define __has_builtin(x) 0
#endif

#define NSTEP 100

// ---- workspace offsets (u32 units) ----
#define ATTIH4_U 0            // 320*256*4
#define ATTHH4_U 327680       // 128*256*4
#define D1IH4_U  458752
#define D1HH4_U  589824
#define D2IH4_U  720896
#define D2HH4_U  851968
#define PKQ_U    983040       // 128*128
#define PKPD_U   999424       // 384*256
#define PKMEL_U  1097728      // 128*560
#define W1T_U    1169408      // 80*256 f32
#define W2T_U    1189888      // 256*128 f32
#define INPT_U   1222656      // 512*128 f32
#define PROCF_U  1288192      // half[64*512*128]
#define P2ALL_U  3385344      // float[100*64*128]
#define HATT_U   4204544      // f32[64*256]
#define H1_U     4220928
#define H2_U     4237312
#define HATTP_U  4253696      // u32[64*128]
#define H1P_U    4261888
#define H2P_U    4270080
#define DEC0_U   4278272
#define DEC1_U   4294656
#define DEC2_U   4311040
#define DEC0P_U  4327424
#define DEC1P_U  4335616
#define DEC2P_U  4343808
#define CTXP_U   4352000      // f32[4][64][512]
#define XCATP_U  4483072      // u32[64*320]
#define ALIGN_U  4503552      // f32[64*512]
#define AWC_U    4536320      // f32[64*512]
#define SRED_U   4569088      // f32[64*8]
#define SRED2_U  4569600      // f32[64*8]
#define CNT_U    4570112
#define STATE_BASE_U 4204544
#define STATE_N   365632
#define XCATP_REL 278528

#define OUT_ATT  3584000
#define OUT_STOP 6860800

typedef _Float16 fh2 __attribute__((ext_vector_type(2)));
union U4 { uint4 v; _Float16 h[8]; };

__device__ __forceinline__ float fastrcp(float x) { return __builtin_amdgcn_rcpf(x); }
__device__ __forceinline__ float sig_p(float x) { return 1.f / (1.f + __expf(-x)); }
__device__ __forceinline__ float tanh_f(float x) {
    x = fminf(fmaxf(x, -15.f), 15.f);
    float e2 = __expf(2.f * x);
    return (e2 - 1.f) * fastrcp(e2 + 1.f);
}
__device__ __forceinline__ float dot2(u32 w, u32 x, float acc) {
    fh2 wh = __builtin_bit_cast(fh2, w);
    fh2 xh = __builtin_bit_cast(fh2, x);
#if __has_builtin(__builtin_amdgcn_fdot2)
    return __builtin_amdgcn_fdot2(wh, xh, acc, false);
#else
    return acc + (float)wh.x * (float)xh.x + (float)wh.y * (float)xh.y;
#endif
}
__device__ __forceinline__ u32 packh2(float a, float b) {
    fh2 h; h.x = (_Float16)a; h.y = (_Float16)b;
    return __builtin_bit_cast(u32, h);
}

// device-wide barrier: monotonic counter, 256 blocks
__device__ __forceinline__ void gridbar(u32* cnt, u32 target, int tid) {
    __syncthreads();
    if (tid == 0) {
        __threadfence();
        __hip_atomic_fetch_add(cnt, 1u, __ATOMIC_ACQ_REL, __HIP_MEMORY_SCOPE_AGENT);
        while (__hip_atomic_load(cnt, __ATOMIC_ACQUIRE, __HIP_MEMORY_SCOPE_AGENT) < target) {
            __builtin_amdgcn_s_sleep(1);
        }
        __threadfence();
    }
    __syncthreads();
}

// ---------------- precompute kernels ----------------

__global__ void tkern(const float* __restrict__ src, float* __restrict__ dst, int O, int K) {
    int i = blockIdx.x * blockDim.x + threadIdx.x;
    if (i < O * K) { int o = i % O, k = i / O; dst[i] = src[o * K + k]; }
}

// pair layout: dst[p*O + o] = f16pair(w[o][2p], w[o][2p+1])
__global__ void packw(const float* __restrict__ src, u32* __restrict__ dst, int O, int K) {
    int i = blockIdx.x * blockDim.x + threadIdx.x;
    int n = O * (K >> 1);
    if (i < n) {
        int o = i % O, p = i / O;
        dst[i] = packh2(src[o * K + 2 * p], src[o * K + 2 * p + 1]);
    }
}

// gate-interleaved uint4 layout for 3-gate GRU weights (src [768][K]):
// dst[(p*256+o)*4 + g] = pair(w[g*256+o][2p], w[g*256+o][2p+1]), dst[..+3]=0
__global__ void packg(const float* __restrict__ src, u32* __restrict__ dst, int K) {
    int i = blockIdx.x * blockDim.x + threadIdx.x;
    int P = K >> 1;
    if (i < P * 256) {
        int o = i & 255, p = i >> 8;
        u32* d = dst + (size_t)i * 4;
#pragma unroll
        for (int g = 0; g < 3; g++)
            d[g] = packh2(src[(g * 256 + o) * K + 2 * p], src[(g * 256 + o) * K + 2 * p + 1]);
        d[3] = 0u;
    }
}

__global__ void prenet_kern(const float* __restrict__ memory,
                            const float* __restrict__ w1T, const float* __restrict__ b1,
                            const float* __restrict__ w2T, const float* __restrict__ b2,
                            float* __restrict__ p2all) {
    __shared__ float mi[80];
    __shared__ float p1[256];
    int blk = blockIdx.x;
    int t = blk >> 6, b = blk & 63;
    int tid = threadIdx.x;
    if (tid < 80) mi[tid] = (t == 0) ? 0.f : memory[(b * 700 + (7 * t - 1)) * 80 + tid];
    __syncthreads();
    float acc = b1[tid];
#pragma unroll 4
    for (int k = 0; k < 80; k++) acc += mi[k] * w1T[k * 256 + tid];
    p1[tid] = fmaxf(acc, 0.f);
    __syncthreads();
    if (tid < 128) {
        float a2 = b2[tid];
#pragma unroll 4
        for (int k = 0; k < 256; k++) a2 += p1[k] * w2T[k * 128 + tid];
        p2all[(t * 64 + b) * 128 + tid] = fmaxf(a2, 0.f);
    }
}

// proc_in -> f16, layout [b][t][a]
__global__ void proc_kern(const float* __restrict__ inputs, const float* __restrict__ inpT,
                          _Float16* __restrict__ procF) {
    __shared__ float xin[8][512];
    int blk = blockIdx.x;
    int b = blk >> 6, t0 = (blk & 63) << 3;
    int tid = threadIdx.x;
    for (int i = tid; i < 8 * 512; i += 1024)
        xin[i >> 9][i & 511] = inputs[((size_t)b * 512 + t0 + (i >> 9)) * 512 + (i & 511)];
    __syncthreads();
    int r = tid >> 7, a = tid & 127;
    float acc = 0.f;
#pragma unroll 4
    for (int d = 0; d < 512; d++) acc += xin[r][d] * inpT[d * 128 + a];
    procF[((size_t)(b * 512) + t0 + r) * 128 + a] = (_Float16)acc;
}

// zero all decoder state; pack p2(step0) into XCATP
__global__ void init_kern(u32* __restrict__ ws) {
    int i = blockIdx.x * blockDim.x + threadIdx.x;
    if (i >= STATE_N) return;
    u32 v = 0u;
    int j = i - XCATP_REL;
    if (j >= 0 && j < 20480) {
        int b = j / 320, k = j % 320;
        if (k < 64) {
            const float* p2 = (const float*)(ws + P2ALL_U) + (size_t)b * 128;
            v = packh2(p2[2 * k], p2[2 * k + 1]);
        }
    }
    ws[STATE_BASE_U + i] = v;
}

// ---------------- persistent decoder ----------------

__launch_bounds__(512, 4)
__global__ void decoder2(const float* __restrict__ inputs,
                         u32* __restrict__ ws,
                         const float* __restrict__ att_b_ih, const float* __restrict__ att_b_hh,
                         const float* __restrict__ v_w, const float* __restrict__ v_b,
                         const float* __restrict__ lcg, const float* __restrict__ lwg,
                         const float* __restrict__ pd_b,
                         const float* __restrict__ d1b_ih, const float* __restrict__ d1b_hh,
                         const float* __restrict__ d2b_ih, const float* __restrict__ d2b_hh,
                         const float* __restrict__ mel_b,
                         const float* __restrict__ stop_w, const float* __restrict__ stop_b,
                         float* __restrict__ out) {
    const int B = blockIdx.x;
    const int tid = threadIdx.x;
    const int b  = B >> 2;          // batch row
    const int os = B & 3;           // output/t slice (XCD-stationary)
    const int t0 = os * 128;
    const int lane = tid & 63;
    const int wv = tid >> 6;        // 8 waves

    const uint4* wA   = (const uint4*)(ws + ATTIH4_U);
    const uint4* wAH  = (const uint4*)(ws + ATTHH4_U);
    const uint4* w1I  = (const uint4*)(ws + D1IH4_U);
    const uint4* w1H  = (const uint4*)(ws + D1HH4_U);
    const uint4* w2I  = (const uint4*)(ws + D2IH4_U);
    const uint4* w2H  = (const uint4*)(ws + D2HH4_U);
    const u32* wQ     = ws + PKQ_U;
    const u32* wPD    = ws + PKPD_U;
    const u32* wMEL   = ws + PKMEL_U;
    const _Float16* procF = (const _Float16*)(ws + PROCF_U);
    const float* p2all = (const float*)(ws + P2ALL_U);
    float* HATT = (float*)(ws + HATT_U);
    float* H1   = (float*)(ws + H1_U);
    float* H2   = (float*)(ws + H2_U);
    u32* HATTP  = ws + HATTP_U;
    u32* H1P    = ws + H1P_U;
    u32* H2P    = ws + H2P_U;
    float* DEC0 = (float*)(ws + DEC0_U);
    float* DEC1 = (float*)(ws + DEC1_U);
    float* DEC2 = (float*)(ws + DEC2_U);
    u32* DEC0P  = ws + DEC0P_U;
    u32* DEC1P  = ws + DEC1P_U;
    u32* DEC2P  = ws + DEC2P_U;
    float* CTXP = (float*)(ws + CTXP_U);
    u32* XCATP  = ws + XCATP_U;
    float* ALGN = (float*)(ws + ALIGN_U);
    float* AWC  = (float*)(ws + AWC_U);
    float* SRED = (float*)(ws + SRED_U);
    float* SRED2= (float*)(ws + SRED2_U);
    u32* cnt    = ws + CNT_U;

    __shared__ float lc[1984];
    __shared__ float eb[128];
    __shared__ u32 xc[320];
    __shared__ u32 xhp[128];
    __shared__ float scr6[3072];     // 8 ks x 6 comps x 64
    __shared__ float hb[64], db[64];
    __shared__ float aw[158], awc[158];
    __shared__ float convbuf[32 * 132];
    __shared__ float pq[128];
    __shared__ float scrE[512];
    __shared__ float redv[8];
    __shared__ float ms[2];
    __shared__ float alb[128];
    __shared__ float scrC[2048];
    __shared__ u32 xp[384];
    __shared__ u32 dp[128], hp[128];
    __shared__ float scrG[420];
    __shared__ float mo[140];

    for (int i = tid; i < 1984; i += 512) lc[i] = lcg[i];
    const float vb0 = v_b[0];
    const float sb0 = stop_b[0];
    u32 ph = 0;
    __syncthreads();

    for (int step = 0; step < NSTEP; step++) {
        // ======== Stage A: attention GRU (outs oabs = os*64 + 0..63) ========
        if (tid < 320) xc[tid] = XCATP[b * 320 + tid];
        else if (tid < 448) xhp[tid - 320] = HATTP[b * 128 + (tid - 320)];
        __syncthreads();
        {
            float air = 0.f, aiz = 0.f, ain = 0.f, ahr = 0.f, ahz = 0.f, ahn = 0.f;
            const int oabs = os * 64 + lane;
#pragma unroll 8
            for (int p = wv * 40; p < wv * 40 + 40; p++) {
                uint4 w = wA[p * 256 + oabs];
                u32 x = xc[p];
                air = dot2(w.x, x, air); aiz = dot2(w.y, x, aiz); ain = dot2(w.z, x, ain);
            }
#pragma unroll 8
            for (int p = wv * 16; p < wv * 16 + 16; p++) {
                uint4 w = wAH[p * 256 + oabs];
                u32 x = xhp[p];
                ahr = dot2(w.x, x, ahr); ahz = dot2(w.y, x, ahz); ahn = dot2(w.z, x, ahn);
            }
            float* s = &scr6[wv * 384 + lane];
            s[0] = air; s[64] = aiz; s[128] = ain; s[192] = ahr; s[256] = ahz; s[320] = ahn;
        }
        __syncthreads();
        if (tid < 64) {
            const int oabs = os * 64 + tid;
            float gr = att_b_ih[oabs], gz = att_b_ih[256 + oabs], gn = att_b_ih[512 + oabs];
            float hr = att_b_hh[oabs], hz = att_b_hh[256 + oabs], hn = att_b_hh[512 + oabs];
#pragma unroll
            for (int k = 0; k < 8; k++) {
                const float* s = &scr6[k * 384 + tid];
                gr += s[0]; gz += s[64]; gn += s[128];
                hr += s[192]; hz += s[256]; hn += s[320];
            }
            float r = sig_p(gr + hr), z = sig_p(gz + hz);
            float n = tanhf(gn + r * hn);
            float h = (1.f - z) * n + z * HATT[b * 256 + oabs];
            HATT[b * 256 + oabs] = h;
            hb[tid] = h;
        }
        __syncthreads();
        if (tid < 32) HATTP[b * 128 + os * 32 + tid] = packh2(hb[2 * tid], hb[2 * tid + 1]);
        ++ph; gridbar(cnt, 256u * ph, tid);                       // BARRIER 1

        // ======== Stage B: pq + conv + energies + softmax partials ========
        if (tid < 128) xhp[tid] = HATTP[b * 128 + tid];
        else if (tid < 286) {
            int j = tid - 128, t = t0 + j - 15;
            aw[j] = (t >= 0 && t < 512) ? ALGN[b * 512 + t] : 0.f;
        } else if (tid < 444) {
            int j = tid - 286, t = t0 + j - 15;
            awc[j] = (t >= 0 && t < 512) ? AWC[b * 512 + t] : 0.f;
        }
        __syncthreads();
        {   // pq partials: 4 ks x 128 n
            const int n = tid & 127, ks = tid >> 7;
            float acc = 0.f;
#pragma unroll 8
            for (int p = ks * 32; p < ks * 32 + 32; p++)
                acc = dot2(wQ[p * 128 + n], xhp[p], acc);
            scrE[ks * 128 + n] = acc;
        }
        __syncthreads();
        {   // conv: 128 t x 4 c-slices of 8
            const int tl = tid & 127, cs = tid >> 7;
#pragma unroll
            for (int c = cs * 8; c < cs * 8 + 8; c++) {
                float s = 0.f;
                const float* l1 = &lc[c * 62];
#pragma unroll
                for (int k = 0; k < 31; k++) s += l1[k] * aw[tl + k] + l1[31 + k] * awc[tl + k];
                convbuf[c * 132 + tl] = s;
            }
            if (tid < 128) pq[tid] = scrE[tid] + scrE[128 + tid] + scrE[256 + tid] + scrE[384 + tid];
        }
        __syncthreads();
        {   // energies: 128 t x 4 a-slices of 32
            const int tl = tid & 127, as = tid >> 7;
            const int a0 = as * 32;
            float cr[32];
#pragma unroll
            for (int c = 0; c < 32; c++) cr[c] = convbuf[c * 132 + tl];
            const uint4* pf = (const uint4*)(procF + ((size_t)(b * 512) + t0 + tl) * 128 + a0);
            float acc = 0.f;
#pragma unroll
            for (int l = 0; l < 4; l++) {
                U4 u; u.v = pf[l];
#pragma unroll
                for (int j = 0; j < 8; j++) {
                    const int a = a0 + l * 8 + j;
                    float s = pq[a] + (float)u.h[j];
#pragma unroll
                    for (int c = 0; c < 32; c++) s += lwg[a * 32 + c] * cr[c];
                    acc += v_w[a] * tanh_f(s);
                }
            }
            scrE[as * 128 + tl] = acc;
        }
        __syncthreads();
        if (tid < 128) {
            float e = scrE[tid] + scrE[128 + tid] + scrE[256 + tid] + scrE[384 + tid] + vb0;
            eb[tid] = e;
            float v = e;
#pragma unroll
            for (int off = 32; off; off >>= 1) v = fmaxf(v, __shfl_down(v, off, 64));
            if ((tid & 63) == 0) redv[tid >> 6] = v;
        }
        __syncthreads();
        if (tid < 128) {
            float m_s = fmaxf(redv[0], redv[1]);
            if (tid == 0) ms[0] = m_s;
            float v = __expf(eb[tid] - m_s);
#pragma unroll
            for (int off = 32; off; off >>= 1) v += __shfl_down(v, off, 64);
            if ((tid & 63) == 0) redv[2 + (tid >> 6)] = v;
        }
        __syncthreads();
        if (tid == 0) {
            SRED[b * 8 + os * 2]     = ms[0];
            SRED[b * 8 + os * 2 + 1] = redv[2] + redv[3];
        }
        ++ph; gridbar(cnt, 256u * ph, tid);                       // BARRIER 2

        // ======== Stage C: softmax finalize + align/awc + ctx partial ========
        if (tid == 0) {
            float M = SRED[b * 8], S;
            for (int s = 1; s < 4; s++) M = fmaxf(M, SRED[b * 8 + 2 * s]);
            S = 0.f;
            for (int s = 0; s < 4; s++) S += SRED[b * 8 + 2 * s + 1] * __expf(SRED[b * 8 + 2 * s] - M);
            ms[0] = M; ms[1] = fastrcp(S);
        }
        __syncthreads();
        if (tid < 128) {
            float al = __expf(eb[tid] - ms[0]) * ms[1];
            const int t = t0 + tid;
            ALGN[b * 512 + t] = al;
            AWC[b * 512 + t] += al;
            out[OUT_ATT + ((size_t)b * 100 + step) * 512 + t] = al;
            alb[tid] = al;
        }
        __syncthreads();
        {   // ctx partial: 4 t-slices x 128 d-groups (4 floats each)
            const int dg = tid & 127, tsl = tid >> 7;
            const float4* in4 = (const float4*)inputs + ((size_t)(b * 512) + t0 + tsl * 32) * 128 + dg;
            float4 acc = {0.f, 0.f, 0.f, 0.f};
#pragma unroll 8
            for (int i = 0; i < 32; i++) {
                float al = alb[tsl * 32 + i];
                float4 x = in4[(size_t)i * 128];
                acc.x += al * x.x; acc.y += al * x.y; acc.z += al * x.z; acc.w += al * x.w;
            }
            *(float4*)&scrC[tsl * 512 + dg * 4] = acc;
        }
        __syncthreads();
        {
            float s = scrC[tid] + scrC[512 + tid] + scrC[1024 + tid] + scrC[1536 + tid];
            CTXP[((size_t)os * 64 + b) * 512 + tid] = s;
        }
        ++ph; gridbar(cnt, 256u * ph, tid);                       // BARRIER 3

        // ======== Stage D: xcat/xppd assembly + pd projection ========
        if (tid < 256) {
            const int j = tid;
            float s0 = 0.f, s1 = 0.f;
#pragma unroll
            for (int s = 0; s < 4; s++) {
                const float* cp = &CTXP[((size_t)s * 64 + b) * 512];
                s0 += cp[2 * j]; s1 += cp[2 * j + 1];
            }
            u32 pr = packh2(s0, s1);
            xp[128 + j] = pr;
            if (os == 0) XCATP[b * 320 + 64 + j] = pr;
        } else if (tid < 384) {
            xp[tid - 256] = HATTP[b * 128 + (tid - 256)];
        } else if (tid < 448 && os == 1 && step + 1 < NSTEP) {
            int j = tid - 384;
            const float* p2n = p2all + ((size_t)(step + 1) * 64 + b) * 128;
            XCATP[b * 320 + j] = packh2(p2n[2 * j], p2n[2 * j + 1]);
        }
        __syncthreads();
        {   // pd: 8 ks x 64 o
            const int oabs = os * 64 + lane;
            float acc = 0.f;
#pragma unroll 8
            for (int p = wv * 48; p < wv * 48 + 48; p++)
                acc = dot2(wPD[p * 256 + oabs], xp[p], acc);
            scr6[wv * 64 + lane] = acc;
        }
        __syncthreads();
        if (tid < 64) {
            const int oabs = os * 64 + tid;
            float d = pd_b[oabs];
#pragma unroll
            for (int k = 0; k < 8; k++) d += scr6[k * 64 + tid];
            DEC0[b * 256 + oabs] = d;
            db[tid] = d;
        }
        __syncthreads();
        if (tid < 32) DEC0P[b * 128 + os * 32 + tid] = packh2(db[2 * tid], db[2 * tid + 1]);
        ++ph; gridbar(cnt, 256u * ph, tid);                       // BARRIER 4

        // ======== Stage E: decoder GRU 1 ========
        if (tid < 128) dp[tid] = DEC0P[b * 128 + tid];
        else if (tid < 256) hp[tid - 128] = H1P[b * 128 + (tid - 128)];
        __syncthreads();
        {
            float air = 0.f, aiz = 0.f, ain = 0.f, ahr = 0.f, ahz = 0.f, ahn = 0.f;
            const int oabs = os * 64 + lane;
#pragma unroll 8
            for (int p = wv * 16; p < wv * 16 + 16; p++) {
                uint4 wi = w1I[p * 256 + oabs];
                uint4 wh = w1H[p * 256 + oabs];
                u32 xd = dp[p], xh = hp[p];
                air = dot2(wi.x, xd, air); aiz = dot2(wi.y, xd, aiz); ain = dot2(wi.z, xd, ain);
                ahr = dot2(wh.x, xh, ahr); ahz = dot2(wh.y, xh, ahz); ahn = dot2(wh.z, xh, ahn);
            }
            float* s = &scr6[wv * 384 + lane];
            s[0] = air; s[64] = aiz; s[128] = ain; s[192] = ahr; s[256] = ahz; s[320] = ahn;
        }
        __syncthreads();
        if (tid < 64) {
            const int oabs = os * 64 + tid;
            float gr = d1b_ih[oabs], gz = d1b_ih[256 + oabs], gn = d1b_ih[512 + oabs];
            float hr = d1b_hh[oabs], hz = d1b_hh[256 + oabs], hn = d1b_hh[512 + oabs];
#pragma unroll
            for (int k = 0; k < 8; k++) {
                const float* s = &scr6[k * 384 + tid];
                gr += s[0]; gz += s[64]; gn += s[128];
                hr += s[192]; hz += s[256]; hn += s[320];
            }
            float r = sig_p(gr + hr), z = sig_p(gz + hz);
            float n = tanhf(gn + r * hn);
            float h = (1.f - z) * n + z * H1[b * 256 + oabs];
            H1[b * 256 + oabs] = h;
            float d = DEC0[b * 256 + oabs] + h;
            DEC1[b * 256 + oabs] = d;
            hb[tid] = h; db[tid] = d;
        }
        __syncthreads();
        if (tid < 32) {
            H1P[b * 128 + os * 32 + tid]   = packh2(hb[2 * tid], hb[2 * tid + 1]);
            DEC1P[b * 128 + os * 32 + tid] = packh2(db[2 * tid], db[2 * tid + 1]);
        }
        ++ph; gridbar(cnt, 256u * ph, tid);                       // BARRIER 5

        // ======== Stage F: decoder GRU 2 ========
        if (tid < 128) dp[tid] = DEC1P[b * 128 + tid];
        else if (tid < 256) hp[tid - 128] = H2P[b * 128 + (tid - 128)];
        __syncthreads();
        {
            float air = 0.f, aiz = 0.f, ain = 0.f, ahr = 0.f, ahz = 0.f, ahn = 0.f;
            const int oabs = os * 64 + lane;
#pragma unroll 8
            for (int p = wv * 16; p < wv * 16 + 16; p++) {
                uint4 wi = w2I[p * 256 + oabs];
                uint4 wh = w2H[p * 256 + oabs];
                u32 xd = dp[p], xh = hp[p];
                air = dot2(wi.x, xd, air); aiz = dot2(wi.y, xd, aiz); ain = dot2(wi.z, xd, ain);
                ahr = dot2(wh.x, xh, ahr); ahz = dot2(wh.y, xh, ahz); ahn = dot2(wh.z, xh, ahn);
            }
            float* s = &scr6[wv * 384 + lane];
            s[0] = air; s[64] = aiz; s[128] = ain; s[192] = ahr; s[256] = ahz; s[320] = ahn;
        }
        __syncthreads();
        if (tid < 64) {
            const int oabs = os * 64 + tid;
            float gr = d2b_ih[oabs], gz = d2b_ih[256 + oabs], gn = d2b_ih[512 + oabs];
            float hr = d2b_hh[oabs], hz = d2b_hh[256 + oabs], hn = d2b_hh[512 + oabs];
#pragma unroll
            for (int k = 0; k < 8; k++) {
                const float* s = &scr6[k * 384 + tid];
                gr += s[0]; gz += s[64]; gn += s[128];
                hr += s[192]; hz += s[256]; hn += s[320];
            }
            float r = sig_p(gr + hr), z = sig_p(gz + hz);
            float n = tanhf(gn + r * hn);
            float h = (1.f - z) * n + z * H2[b * 256 + oabs];
            H2[b * 256 + oabs] = h;
            float d = DEC1[b * 256 + oabs] + h;
            DEC2[b * 256 + oabs] = d;
            hb[tid] = h; db[tid] = d;
        }
        __syncthreads();
        if (tid < 32) {
            H2P[b * 128 + os * 32 + tid]   = packh2(hb[2 * tid], hb[2 * tid + 1]);
            DEC2P[b * 128 + os * 32 + tid] = packh2(db[2 * tid], db[2 * tid + 1]);
        }
        ++ph; gridbar(cnt, 256u * ph, tid);                       // BARRIER 6

        // ======== Stage G: mel (slice of 140) + stop partials ========
        if (tid < 128) dp[tid] = DEC2P[b * 128 + tid];
        __syncthreads();
        if (tid < 420) {
            const int oi = tid % 140, ks = tid / 140;
            const int oabs = os * 140 + oi;
            const int p0 = ks * 43, pc = (ks == 2) ? 42 : 43;
            float acc = 0.f;
#pragma unroll 8
            for (int p = p0; p < p0 + pc; p++)
                acc = dot2(wMEL[p * 560 + oabs], dp[p], acc);
            scrG[ks * 140 + oi] = acc;
        }
        __syncthreads();
        if (tid < 140) {
            const int oabs = os * 140 + tid;
            float m = mel_b[oabs] + scrG[tid] + scrG[140 + tid] + scrG[280 + tid];
            mo[tid] = m;
            int mm = oabs % 80, jj = oabs / 80;
            out[((size_t)b * 80 + mm) * 700 + 7 * step + jj] = m;
        }
        __syncthreads();
        if (tid < 64) {
            const int l = tid;
            float v = mo[l] * stop_w[256 + os * 140 + l]
                    + mo[64 + l] * stop_w[256 + os * 140 + 64 + l];
            if (l < 12) v += mo[128 + l] * stop_w[256 + os * 140 + 128 + l];
#pragma unroll
            for (int off = 32; off; off >>= 1) v += __shfl_down(v, off, 64);
            if (l == 0) SRED2[b * 8 + os] = v;
        } else if (tid < 128 && os == 0) {
            const int l = tid - 64;
            float v = 0.f;
#pragma unroll
            for (int g = 0; g < 4; g++)
                v += DEC2[b * 256 + l + 64 * g] * stop_w[l + 64 * g];
#pragma unroll
            for (int off = 32; off; off >>= 1) v += __shfl_down(v, off, 64);
            if (l == 0) SRED2[b * 8 + 4] = v;
        }
        ++ph; gridbar(cnt, 256u * ph, tid);                       // BARRIER 7

        // ======== Stage H: stop finalize (overlaps next step's Stage A) ====
        if (os == 0 && tid == 0) {
            float s = sb0 + SRED2[b * 8] + SRED2[b * 8 + 1] + SRED2[b * 8 + 2]
                    + SRED2[b * 8 + 3] + SRED2[b * 8 + 4];
            out[OUT_STOP + (size_t)b * 100 + step] = s;
        }
    }
}

extern "C" void kernel_launch(void* const* d_in, const int* in_sizes, int n_in,
                              void* d_out, int out_size, void* d_ws, size_t ws_size,
                              hipStream_t stream) {
    const float* inputs    = (const float*)d_in[0];
    const float* memory    = (const float*)d_in[1];
    const float* prenet_w1 = (const float*)d_in[3];
    const float* prenet_b1 = (const float*)d_in[4];
    const float* prenet_w2 = (const float*)d_in[5];
    const float* prenet_b2 = (const float*)d_in[6];
    const float* att_w_ih  = (const float*)d_in[7];
    const float* att_w_hh  = (const float*)d_in[8];
    const float* att_b_ih  = (const float*)d_in[9];
    const float* att_b_hh  = (const float*)d_in[10];
    const float* q_w       = (const float*)d_in[11];
    const float* inp_w     = (const float*)d_in[12];
    const float* v_w       = (const float*)d_in[13];
    const float* v_b       = (const float*)d_in[14];
    const float* loc_conv  = (const float*)d_in[15];
    const float* loc_w     = (const float*)d_in[16];
    const float* pd_w      = (const float*)d_in[17];
    const float* pd_b      = (const float*)d_in[18];
    const float* d1_w_ih   = (const float*)d_in[19];
    const float* d1_w_hh   = (const float*)d_in[20];
    const float* d1_b_ih   = (const float*)d_in[21];
    const float* d1_b_hh   = (const float*)d_in[22];
    const float* d2_w_ih   = (const float*)d_in[23];
    const float* d2_w_hh   = (const float*)d_in[24];
    const float* d2_b_ih   = (const float*)d_in[25];
    const float* d2_b_hh   = (const float*)d_in[26];
    const float* mel_w     = (const float*)d_in[27];
    const float* mel_b     = (const float*)d_in[28];
    const float* stop_w    = (const float*)d_in[29];
    const float* stop_b    = (const float*)d_in[30];

    u32* wsu = (u32*)d_ws;
    float* out = (float*)d_out;

    // gate-interleaved packs (3-gate GRU weights)
    packg<<<(320 * 256 + 255) / 256, 256, 0, stream>>>(att_w_ih, wsu + ATTIH4_U, 640);
    packg<<<(128 * 256 + 255) / 256, 256, 0, stream>>>(att_w_hh, wsu + ATTHH4_U, 256);
    packg<<<(128 * 256 + 255) / 256, 256, 0, stream>>>(d1_w_ih,  wsu + D1IH4_U, 256);
    packg<<<(128 * 256 + 255) / 256, 256, 0, stream>>>(d1_w_hh,  wsu + D1HH4_U, 256);
    packg<<<(128 * 256 + 255) / 256, 256, 0, stream>>>(d2_w_ih,  wsu + D2IH4_U, 256);
    packg<<<(128 * 256 + 255) / 256, 256, 0, stream>>>(d2_w_hh,  wsu + D2HH4_U, 256);
    // pair packs (single-output projections)
    packw<<<(128 * 128 + 255) / 256, 256, 0, stream>>>(q_w,   wsu + PKQ_U,   128, 256);
    packw<<<(384 * 256 + 255) / 256, 256, 0, stream>>>(pd_w,  wsu + PKPD_U,  256, 768);
    packw<<<(128 * 560 + 255) / 256, 256, 0, stream>>>(mel_w, wsu + PKMEL_U, 560, 256);
    // fp32 transposes for prenet / proc
    tkern<<<(256 * 80 + 255) / 256, 256, 0, stream>>>(prenet_w1, (float*)(wsu + W1T_U), 256, 80);
    tkern<<<(128 * 256 + 255) / 256, 256, 0, stream>>>(prenet_w2, (float*)(wsu + W2T_U), 128, 256);
    tkern<<<(128 * 512 + 255) / 256, 256, 0, stream>>>(inp_w, (float*)(wsu + INPT_U), 128, 512);

    prenet_kern<<<6400, 256, 0, stream>>>(memory, (float*)(wsu + W1T_U), prenet_b1,
                                          (float*)(wsu + W2T_U), prenet_b2,
                                          (float*)(wsu + P2ALL_U));
    proc_kern<<<4096, 1024, 0, stream>>>(inputs, (float*)(wsu + INPT_U),
                                         (_Float16*)(wsu + PROCF_U));
    init_kern<<<(STATE_N + 255) / 256, 256, 0, stream>>>(wsu);

    decoder2<<<256, 512, 0, stream>>>(inputs, wsu,
                                      att_b_ih, att_b_hh, v_w, v_b,
                                      loc_conv, loc_w, pd_b,
                                      d1_b_ih, d1_b_hh, d2_b_ih, d2_b_hh,
                                      mel_b, stop_w, stop_b, out);
}

// Round 5
// 20120.679 us; speedup vs baseline: 2.4520x; 2.4520x over previous
//
#include <hip/hip_runtime.h>
#include <hip/hip_bf16.h>

// ---------------------------------------------------------------------------
// Decoder (Tacotron-style) on MI355X. Round 4: R2 structure (64 persistent
// blocks, no grid sync) + L2-residency fixes:
// - nontemporal loads for the streaming reads (inputs in ctx, procF in
//   energies) so the shared 3.7MB f16 weight set stays L2-resident
// - deeper unrolls (16) in GEMV k-loops for more loads in flight
// ---------------------------------------------------------------------------

typedef unsigned int u32;

#ifndef __has_builtin
#define __has_builtin(x) 0
#endif

#define NSTEP 100

// workspace offsets in 4-byte units
#define PK_ATTIH 0                      // 320*768
#define PK_ATTHH 245760                 // 128*768
#define PK_Q     344064                 // 128*128
#define PK_PD    360448                 // 384*256
#define PK_D1IH  458752                 // 128*768
#define PK_D1HH  557056
#define PK_D2IH  655360
#define PK_D2HH  753664
#define PK_MEL   851968                 // 128*560
#define W1T_U    923648                 // 80*256 fp32
#define W2T_U    944128                 // 256*128 fp32
#define PROCF_U  976896                 // half[64*512*128] = 2097152 u32
#define P2ALL_U  3074048                // float[100*64*128]
// + inpT tail after P2ALL (see launch)

#define OUT_ATT  3584000
#define OUT_STOP 6860800

typedef _Float16 h2 __attribute__((ext_vector_type(2)));
typedef float fv4 __attribute__((ext_vector_type(4)));
typedef unsigned int uv4 __attribute__((ext_vector_type(4)));
union U4 { uint4 v; _Float16 h[8]; };

__device__ __forceinline__ float fastrcp(float x) { return __builtin_amdgcn_rcpf(x); }
__device__ __forceinline__ float sig_p(float x) { return 1.f / (1.f + __expf(-x)); }
__device__ __forceinline__ float tanh_f(float x) {
    x = fminf(fmaxf(x, -15.f), 15.f);
    float e2 = __expf(2.f * x);
    return (e2 - 1.f) * fastrcp(e2 + 1.f);
}

__device__ __forceinline__ float dot2(u32 w, u32 x, float acc) {
    h2 wh = __builtin_bit_cast(h2, w);
    h2 xh = __builtin_bit_cast(h2, x);
#if __has_builtin(__builtin_amdgcn_fdot2)
    return __builtin_amdgcn_fdot2(wh, xh, acc, false);
#else
    return acc + (float)wh.x * (float)xh.x + (float)wh.y * (float)xh.y;
#endif
}

__device__ __forceinline__ u32 packh2(float a, float b) {
    h2 h; h.x = (_Float16)a; h.y = (_Float16)b;
    return __builtin_bit_cast(u32, h);
}

// nontemporal (evict-first) vector loads — keep streams out of L2
__device__ __forceinline__ float4 ntload_f4(const float4* p) {
    fv4 v = __builtin_nontemporal_load((const fv4*)p);
    float4 r; r.x = v.x; r.y = v.y; r.z = v.z; r.w = v.w; return r;
}
__device__ __forceinline__ uint4 ntload_u4(const uint4* p) {
    uv4 v = __builtin_nontemporal_load((const uv4*)p);
    uint4 r; r.x = v.x; r.y = v.y; r.z = v.z; r.w = v.w; return r;
}

// transpose: src (O x K) row-major -> dst (K x O)
__global__ void tkern(const float* __restrict__ src, float* __restrict__ dst, int O, int K) {
    int i = blockIdx.x * blockDim.x + threadIdx.x;
    if (i < O * K) {
        int o = i % O, k = i / O;
        dst[i] = src[o * K + k];
    }
}

// pack fp32 (O x K) -> f16 pairs: dst[(k/2)*O + o] = (w[o][2p], w[o][2p+1])
__global__ void packw(const float* __restrict__ src, u32* __restrict__ dst, int O, int K) {
    int i = blockIdx.x * blockDim.x + threadIdx.x;
    int n = O * (K >> 1);
    if (i < n) {
        int o = i % O, p = i / O;
        dst[i] = packh2(src[o * K + 2 * p], src[o * K + 2 * p + 1]);
    }
}

__global__ void prenet_kern(const float* __restrict__ memory,
                            const float* __restrict__ w1T, const float* __restrict__ b1,
                            const float* __restrict__ w2T, const float* __restrict__ b2,
                            float* __restrict__ p2all) {
    __shared__ float mi[80];
    __shared__ float p1[256];
    int blk = blockIdx.x;
    int t = blk >> 6, b = blk & 63;
    int tid = threadIdx.x;
    if (tid < 80) mi[tid] = (t == 0) ? 0.f : memory[(b * 700 + (7 * t - 1)) * 80 + tid];
    __syncthreads();
    float acc = b1[tid];
#pragma unroll 4
    for (int k = 0; k < 80; k++) acc += mi[k] * w1T[k * 256 + tid];
    p1[tid] = fmaxf(acc, 0.f);
    __syncthreads();
    if (tid < 128) {
        float a2 = b2[tid];
#pragma unroll 4
        for (int k = 0; k < 256; k++) a2 += p1[k] * w2T[k * 128 + tid];
        p2all[(t * 64 + b) * 128 + tid] = fmaxf(a2, 0.f);
    }
}

// proc_in -> f16, layout [b][t][a]
__global__ void proc_kern(const float* __restrict__ inputs, const float* __restrict__ inpT,
                          _Float16* __restrict__ procF) {
    __shared__ float xin[8][512];
    int blk = blockIdx.x;
    int b = blk >> 6, t0 = (blk & 63) << 3;
    int tid = threadIdx.x;
    for (int i = tid; i < 8 * 512; i += 1024)
        xin[i >> 9][i & 511] = inputs[((size_t)b * 512 + t0 + (i >> 9)) * 512 + (i & 511)];
    __syncthreads();
    int r = tid >> 7, a = tid & 127;
    float acc = 0.f;
#pragma unroll 4
    for (int d = 0; d < 512; d++) acc += xin[r][d] * inpT[d * 128 + a];
    procF[((size_t)(b * 512) + t0 + r) * 128 + a] = (_Float16)acc;
}

__launch_bounds__(1024, 1)
__global__ void decoder_kern(const float* __restrict__ inputs,
                             const u32* __restrict__ wsu,
                             const float* __restrict__ att_b_ih, const float* __restrict__ att_b_hh,
                             const float* __restrict__ v_w, const float* __restrict__ v_b,
                             const float* __restrict__ lcg, const float* __restrict__ lwg,
                             const float* __restrict__ pd_b,
                             const float* __restrict__ d1b_ih, const float* __restrict__ d1b_hh,
                             const float* __restrict__ d2b_ih, const float* __restrict__ d2b_hh,
                             const float* __restrict__ mel_b,
                             const float* __restrict__ stop_w, const float* __restrict__ stop_b,
                             float* __restrict__ out) {
    const int b = blockIdx.x;
    const int tid = threadIdx.x;

    const uint4* w_attih = (const uint4*)(wsu + PK_ATTIH);
    const uint4* w_atthh = (const uint4*)(wsu + PK_ATTHH);
    const uint4* w_q     = (const uint4*)(wsu + PK_Q);
    const uint4* w_pd    = (const uint4*)(wsu + PK_PD);
    const uint4* w_d1ih  = (const uint4*)(wsu + PK_D1IH);
    const uint4* w_d1hh  = (const uint4*)(wsu + PK_D1HH);
    const uint4* w_d2ih  = (const uint4*)(wsu + PK_D2IH);
    const uint4* w_d2hh  = (const uint4*)(wsu + PK_D2HH);
    const uint4* w_mel   = (const uint4*)(wsu + PK_MEL);
    const _Float16* procF = (const _Float16*)(wsu + PROCF_U);
    const float* p2all   = (const float*)(wsu + P2ALL_U);

    __shared__ float h_att[256], h1[256], h2[256], dec[256];
    __shared__ float awp[542], awcp[542];
    __shared__ float pq[128], ebuf[512], red[32], mout[560];
    __shared__ float convbuf[32 * 513];
    __shared__ __align__(16) float scrA[4096];
    __shared__ __align__(16) float scrB[3072];
    __shared__ u32 xpatt[320];   // [p2 pairs 0..63 | ctx pairs 64..319]
    __shared__ u32 xppd[384];    // [h_att pairs 0..127 | ctx pairs 128..383]
    __shared__ u32 decp[128], h1p[128], h2p[128];

    for (int i = tid; i < 256; i += 1024) { h_att[i] = 0.f; h1[i] = 0.f; h2[i] = 0.f; dec[i] = 0.f; }
    for (int i = tid; i < 542; i += 1024) { awp[i] = 0.f; awcp[i] = 0.f; }
    for (int i = tid; i < 320; i += 1024) xpatt[i] = 0u;
    for (int i = tid; i < 384; i += 1024) xppd[i] = 0u;
    if (tid < 128) { decp[tid] = 0u; h1p[tid] = 0u; h2p[tid] = 0u; }
    if (tid >= 960) {   // pack p2 for step 0
        int j = tid - 960;
        xpatt[j] = packh2(p2all[(size_t)b * 128 + 2 * j], p2all[(size_t)b * 128 + 2 * j + 1]);
    }
    const float vb0 = v_b[0];
    const float sb0 = stop_b[0];
    __syncthreads();

    for (int step = 0; step < NSTEP; step++) {
        // ---- R1: att-GRU gate partials (768 thr: 192 og x 4 ks) ----
        if (tid < 768) {
            const int og = tid % 192;
            const int ks = tid / 192;
            float4 ai = {0.f, 0.f, 0.f, 0.f};
            float4 ah4 = {0.f, 0.f, 0.f, 0.f};
#pragma unroll 16
            for (int p = ks * 80; p < ks * 80 + 80; p++) {
                uint4 w = w_attih[p * 192 + og];
                u32 x = xpatt[p];
                ai.x = dot2(w.x, x, ai.x); ai.y = dot2(w.y, x, ai.y);
                ai.z = dot2(w.z, x, ai.z); ai.w = dot2(w.w, x, ai.w);
            }
#pragma unroll 16
            for (int p = ks * 32; p < ks * 32 + 32; p++) {
                uint4 w = w_atthh[p * 192 + og];
                u32 x = xppd[p];
                ah4.x = dot2(w.x, x, ah4.x); ah4.y = dot2(w.y, x, ah4.y);
                ah4.z = dot2(w.z, x, ah4.z); ah4.w = dot2(w.w, x, ah4.w);
            }
            *(float4*)&scrA[ks * 768 + og * 4] = ai;
            *(float4*)&scrB[ks * 768 + og * 4] = ah4;
        }
        __syncthreads();

        // ---- R2: att-GRU combine (128 thr x 2 outputs) + pack h_att pairs ----
        if (tid < 128) {
            float hv[2];
#pragma unroll
            for (int j = 0; j < 2; j++) {
                const int o = tid * 2 + j;
                float gr = att_b_ih[o], gz = att_b_ih[256 + o], gn = att_b_ih[512 + o];
                float hr = att_b_hh[o], hz = att_b_hh[256 + o], hn = att_b_hh[512 + o];
#pragma unroll
                for (int s = 0; s < 4; s++) {
                    gr += scrA[s * 768 + o]; gz += scrA[s * 768 + 256 + o]; gn += scrA[s * 768 + 512 + o];
                    hr += scrB[s * 768 + o]; hz += scrB[s * 768 + 256 + o]; hn += scrB[s * 768 + 512 + o];
                }
                float r = sig_p(gr + hr), z = sig_p(gz + hz);
                float n = tanhf(gn + r * hn);
                hv[j] = (1.f - z) * n + z * h_att[o];
                h_att[o] = hv[j];
            }
            xppd[tid] = packh2(hv[0], hv[1]);
        }
        __syncthreads();

        // ---- R3: q partials (128 thr) || location conv (512 thr) ----
        if (tid < 128) {
            const int og = tid & 31, ks = tid >> 5;
            float4 acc = {0.f, 0.f, 0.f, 0.f};
#pragma unroll 16
            for (int p = ks * 32; p < ks * 32 + 32; p++) {
                uint4 w = w_q[p * 32 + og];
                u32 x = xppd[p];
                acc.x = dot2(w.x, x, acc.x); acc.y = dot2(w.y, x, acc.y);
                acc.z = dot2(w.z, x, acc.z); acc.w = dot2(w.w, x, acc.w);
            }
            *(float4*)&scrA[ks * 128 + og * 4] = acc;
        } else if (tid >= 512) {
            const int tp = tid - 512;
            float cr[32];
#pragma unroll
            for (int c = 0; c < 32; c++) cr[c] = 0.f;
            for (int k = 0; k < 31; k++) {
                float a1 = awp[tp + k], a2 = awcp[tp + k];
#pragma unroll
                for (int c = 0; c < 32; c++)
                    cr[c] += lcg[c * 62 + k] * a1 + lcg[c * 62 + 31 + k] * a2;
            }
#pragma unroll
            for (int c = 0; c < 32; c++) convbuf[c * 513 + tp] = cr[c];
        }
        __syncthreads();

        // ---- R4: pq reduce ----
        if (tid < 128) {
            pq[tid] = scrA[tid] + scrA[128 + tid] + scrA[256 + tid] + scrA[384 + tid];
        }
        __syncthreads();

        // ---- R5: attention energies (1024 thr: 512 t x 2 a-halves) ----
        {
            const int tp = tid & 511;
            const int ah = tid >> 9;                    // wave-uniform
            const int a0 = ah * 64;
            float cr2[32];
#pragma unroll
            for (int c = 0; c < 32; c++) cr2[c] = convbuf[c * 513 + tp];
            const uint4* pf4 = (const uint4*)(procF + ((size_t)(b * 512 + tp)) * 128 + a0);
            float acc = 0.f;
            for (int l = 0; l < 8; l++) {
                U4 u; u.v = ntload_u4(&pf4[l]);
#pragma unroll
                for (int j = 0; j < 8; j++) {
                    const int a = l * 8 + j;
                    float s = pq[a0 + a] + (float)u.h[j];
#pragma unroll
                    for (int c = 0; c < 32; c++) s += lwg[(a0 + a) * 32 + c] * cr2[c];
                    acc += v_w[a0 + a] * tanh_f(s);
                }
            }
            scrB[tid] = acc;
        }
        __syncthreads();

        // ---- R6: softmax over 512 + aw/awc + atts output ----
        float e_reg = -1e30f;
        if (tid < 512) e_reg = scrB[tid] + scrB[512 + tid] + vb0;
        {
            float v = e_reg;
#pragma unroll
            for (int off = 32; off; off >>= 1) v = fmaxf(v, __shfl_down(v, off, 64));
            if (tid < 512 && (tid & 63) == 0) red[tid >> 6] = v;
        }
        __syncthreads();
        if (tid == 0) {
            float m = red[0];
            for (int w = 1; w < 8; w++) m = fmaxf(m, red[w]);
            red[16] = m;
        }
        __syncthreads();
        float ex = 0.f;
        if (tid < 512) ex = __expf(e_reg - red[16]);
        {
            float v = ex;
#pragma unroll
            for (int off = 32; off; off >>= 1) v += __shfl_down(v, off, 64);
            if (tid < 512 && (tid & 63) == 0) red[tid >> 6] = v;
        }
        __syncthreads();
        if (tid == 0) {
            float s = 0.f;
            for (int w = 0; w < 8; w++) s += red[w];
            red[17] = s;
        }
        __syncthreads();
        if (tid < 512) {
            float al = ex * fastrcp(red[17]);
            ebuf[tid] = al;
            awp[15 + tid] = al;
            awcp[15 + tid] += al;
            out[OUT_ATT + ((size_t)b * 100 + step) * 512 + tid] = al;
        }
        __syncthreads();

        // ---- R7: ctx partials (1024 thr: 128 dg x 8 ts), nontemporal ----
        {
            const int dg = tid & 127, ts = tid >> 7;
            const float4* ib = (const float4*)(inputs + ((size_t)b * 512 + ts * 64) * 512);
            float4 acc = {0.f, 0.f, 0.f, 0.f};
#pragma unroll 8
            for (int t = 0; t < 64; t++) {
                float al = ebuf[ts * 64 + t];
                float4 xv = ntload_f4(&ib[(size_t)t * 128 + dg]);
                acc.x += al * xv.x; acc.y += al * xv.y; acc.z += al * xv.z; acc.w += al * xv.w;
            }
            *(float4*)&scrA[ts * 512 + dg * 4] = acc;
        }
        __syncthreads();

        // ---- R8: ctx reduce + pack pairs ----
        if (tid < 256) {
            float s0 = 0.f, s1 = 0.f;
#pragma unroll
            for (int q = 0; q < 8; q++) { s0 += scrA[q * 512 + 2 * tid]; s1 += scrA[q * 512 + 2 * tid + 1]; }
            u32 pr = packh2(s0, s1);
            xpatt[64 + tid] = pr;
            xppd[128 + tid] = pr;
        }
        __syncthreads();

        // ---- R9: pd partials (1024 thr: 64 og x 16 ks) ----
        {
            const int og = tid & 63, ks = tid >> 6;
            float4 acc = {0.f, 0.f, 0.f, 0.f};
#pragma unroll 8
            for (int p = ks * 24; p < ks * 24 + 24; p++) {
                uint4 w = w_pd[p * 64 + og];
                u32 x = xppd[p];
                acc.x = dot2(w.x, x, acc.x); acc.y = dot2(w.y, x, acc.y);
                acc.z = dot2(w.z, x, acc.z); acc.w = dot2(w.w, x, acc.w);
            }
            *(float4*)&scrA[ks * 256 + og * 4] = acc;
        }
        __syncthreads();

        // ---- R10: dec combine + pack ----
        if (tid < 128) {
            float d0 = pd_b[2 * tid], d1 = pd_b[2 * tid + 1];
#pragma unroll
            for (int q = 0; q < 16; q++) { d0 += scrA[q * 256 + 2 * tid]; d1 += scrA[q * 256 + 2 * tid + 1]; }
            dec[2 * tid] = d0; dec[2 * tid + 1] = d1;
            decp[tid] = packh2(d0, d1);
        }
        __syncthreads();

        // ---- R11: GRU1 partials ----
        if (tid < 768) {
            const int og = tid % 192;
            const int ks = tid / 192;
            float4 ai = {0.f, 0.f, 0.f, 0.f};
            float4 ah4 = {0.f, 0.f, 0.f, 0.f};
#pragma unroll 16
            for (int p = ks * 32; p < ks * 32 + 32; p++) {
                uint4 w1 = w_d1ih[p * 192 + og];
                uint4 w2 = w_d1hh[p * 192 + og];
                u32 xd = decp[p], xh = h1p[p];
                ai.x = dot2(w1.x, xd, ai.x); ai.y = dot2(w1.y, xd, ai.y);
                ai.z = dot2(w1.z, xd, ai.z); ai.w = dot2(w1.w, xd, ai.w);
                ah4.x = dot2(w2.x, xh, ah4.x); ah4.y = dot2(w2.y, xh, ah4.y);
                ah4.z = dot2(w2.z, xh, ah4.z); ah4.w = dot2(w2.w, xh, ah4.w);
            }
            *(float4*)&scrA[ks * 768 + og * 4] = ai;
            *(float4*)&scrB[ks * 768 + og * 4] = ah4;
        }
        __syncthreads();

        // ---- R12: GRU1 combine + residual + pack ----
        if (tid < 128) {
            float hv[2], dv[2];
#pragma unroll
            for (int j = 0; j < 2; j++) {
                const int o = tid * 2 + j;
                float gr = d1b_ih[o], gz = d1b_ih[256 + o], gn = d1b_ih[512 + o];
                float hr = d1b_hh[o], hz = d1b_hh[256 + o], hn = d1b_hh[512 + o];
#pragma unroll
                for (int s = 0; s < 4; s++) {
                    gr += scrA[s * 768 + o]; gz += scrA[s * 768 + 256 + o]; gn += scrA[s * 768 + 512 + o];
                    hr += scrB[s * 768 + o]; hz += scrB[s * 768 + 256 + o]; hn += scrB[s * 768 + 512 + o];
                }
                float r = sig_p(gr + hr), z = sig_p(gz + hz);
                float n = tanhf(gn + r * hn);
                hv[j] = (1.f - z) * n + z * h1[o];
                h1[o] = hv[j];
                dv[j] = hv[j] + dec[o];
                dec[o] = dv[j];
            }
            h1p[tid] = packh2(hv[0], hv[1]);
            decp[tid] = packh2(dv[0], dv[1]);
        }
        __syncthreads();

        // ---- R13: GRU2 partials ----
        if (tid < 768) {
            const int og = tid % 192;
            const int ks = tid / 192;
            float4 ai = {0.f, 0.f, 0.f, 0.f};
            float4 ah4 = {0.f, 0.f, 0.f, 0.f};
#pragma unroll 16
            for (int p = ks * 32; p < ks * 32 + 32; p++) {
                uint4 w1 = w_d2ih[p * 192 + og];
                uint4 w2 = w_d2hh[p * 192 + og];
                u32 xd = decp[p], xh = h2p[p];
                ai.x = dot2(w1.x, xd, ai.x); ai.y = dot2(w1.y, xd, ai.y);
                ai.z = dot2(w1.z, xd, ai.z); ai.w = dot2(w1.w, xd, ai.w);
                ah4.x = dot2(w2.x, xh, ah4.x); ah4.y = dot2(w2.y, xh, ah4.y);
                ah4.z = dot2(w2.z, xh, ah4.z); ah4.w = dot2(w2.w, xh, ah4.w);
            }
            *(float4*)&scrA[ks * 768 + og * 4] = ai;
            *(float4*)&scrB[ks * 768 + og * 4] = ah4;
        }
        __syncthreads();

        // ---- R14: GRU2 combine + residual + pack ----
        if (tid < 128) {
            float hv[2], dv[2];
#pragma unroll
            for (int j = 0; j < 2; j++) {
                const int o = tid * 2 + j;
                float gr = d2b_ih[o], gz = d2b_ih[256 + o], gn = d2b_ih[512 + o];
                float hr = d2b_hh[o], hz = d2b_hh[256 + o], hn = d2b_hh[512 + o];
#pragma unroll
                for (int s = 0; s < 4; s++) {
                    gr += scrA[s * 768 + o]; gz += scrA[s * 768 + 256 + o]; gn += scrA[s * 768 + 512 + o];
                    hr += scrB[s * 768 + o]; hz += scrB[s * 768 + 256 + o]; hn += scrB[s * 768 + 512 + o];
                }
                float r = sig_p(gr + hr), z = sig_p(gz + hz);
                float n = tanhf(gn + r * hn);
                hv[j] = (1.f - z) * n + z * h2[o];
                h2[o] = hv[j];
                dv[j] = hv[j] + dec[o];
                dec[o] = dv[j];
            }
            h2p[tid] = packh2(hv[0], hv[1]);
            decp[tid] = packh2(dv[0], dv[1]);
        }
        __syncthreads();

        // ---- R15: mel partials (560 thr: 140 og x 4 ks) ----
        if (tid < 560) {
            const int og = tid % 140;
            const int ks = tid / 140;
            float4 acc = {0.f, 0.f, 0.f, 0.f};
#pragma unroll 16
            for (int p = ks * 32; p < ks * 32 + 32; p++) {
                uint4 w = w_mel[p * 140 + og];
                u32 x = decp[p];
                acc.x = dot2(w.x, x, acc.x); acc.y = dot2(w.y, x, acc.y);
                acc.z = dot2(w.z, x, acc.z); acc.w = dot2(w.w, x, acc.w);
            }
            *(float4*)&scrA[ks * 560 + og * 4] = acc;
        }
        __syncthreads();

        // ---- R16: mel reduce + output write (280 thr x 2 outputs) ----
        if (tid < 280) {
#pragma unroll
            for (int j = 0; j < 2; j++) {
                const int o = 2 * tid + j;
                float m = mel_b[o];
#pragma unroll
                for (int s = 0; s < 4; s++) m += scrA[s * 560 + o];
                mout[o] = m;
                int mm = o % 80, jj = o / 80;
                out[((size_t)b * 80 + mm) * 700 + 7 * step + jj] = m;
            }
        }
        __syncthreads();

        // ---- R17: stop token || prefetch+pack next p2 ----
        {
            float v = 0.f;
            if (tid < 816) v = ((tid < 256) ? dec[tid] : mout[tid - 256]) * stop_w[tid];
            if (tid < 832) {
#pragma unroll
                for (int off = 32; off; off >>= 1) v += __shfl_down(v, off, 64);
                if ((tid & 63) == 0) red[tid >> 6] = v;
            }
            if (tid >= 960 && step + 1 < NSTEP) {
                int j = tid - 960;
                const float* p2n = p2all + ((size_t)(step + 1) * 64 + b) * 128;
                xpatt[j] = packh2(p2n[2 * j], p2n[2 * j + 1]);
            }
        }
        __syncthreads();
        if (tid == 0) {
            float s = sb0;
            for (int w = 0; w < 13; w++) s += red[w];
            out[OUT_STOP + (size_t)b * 100 + step] = s;
        }
        __syncthreads();
    }
}

extern "C" void kernel_launch(void* const* d_in, const int* in_sizes, int n_in,
                              void* d_out, int out_size, void* d_ws, size_t ws_size,
                              hipStream_t stream) {
    const float* inputs    = (const float*)d_in[0];
    const float* memory    = (const float*)d_in[1];
    const float* prenet_w1 = (const float*)d_in[3];
    const float* prenet_b1 = (const float*)d_in[4];
    const float* prenet_w2 = (const float*)d_in[5];
    const float* prenet_b2 = (const float*)d_in[6];
    const float* att_w_ih  = (const float*)d_in[7];
    const float* att_w_hh  = (const float*)d_in[8];
    const float* att_b_ih  = (const float*)d_in[9];
    const float* att_b_hh  = (const float*)d_in[10];
    const float* q_w       = (const float*)d_in[11];
    const float* inp_w     = (const float*)d_in[12];
    const float* v_w       = (const float*)d_in[13];
    const float* v_b       = (const float*)d_in[14];
    const float* loc_conv  = (const float*)d_in[15];
    const float* loc_w     = (const float*)d_in[16];
    const float* pd_w      = (const float*)d_in[17];
    const float* pd_b      = (const float*)d_in[18];
    const float* d1_w_ih   = (const float*)d_in[19];
    const float* d1_w_hh   = (const float*)d_in[20];
    const float* d1_b_ih   = (const float*)d_in[21];
    const float* d1_b_hh   = (const float*)d_in[22];
    const float* d2_w_ih   = (const float*)d_in[23];
    const float* d2_w_hh   = (const float*)d_in[24];
    const float* d2_b_ih   = (const float*)d_in[25];
    const float* d2_b_hh   = (const float*)d_in[26];
    const float* mel_w     = (const float*)d_in[27];
    const float* mel_b     = (const float*)d_in[28];
    const float* stop_w    = (const float*)d_in[29];
    const float* stop_b    = (const float*)d_in[30];

    u32* wsu = (u32*)d_ws;
    float* out = (float*)d_out;

    auto P = [&](const float* src, int off, int O, int K) {
        int n = O * (K / 2);
        packw<<<(n + 255) / 256, 256, 0, stream>>>(src, wsu + off, O, K);
    };
    P(att_w_ih, PK_ATTIH, 768, 640);
    P(att_w_hh, PK_ATTHH, 768, 256);
    P(q_w,      PK_Q,     128, 256);
    P(pd_w,     PK_PD,    256, 768);
    P(d1_w_ih,  PK_D1IH,  768, 256);
    P(d1_w_hh,  PK_D1HH,  768, 256);
    P(d2_w_ih,  PK_D2IH,  768, 256);
    P(d2_w_hh,  PK_D2HH,  768, 256);
    P(mel_w,    PK_MEL,   560, 256);

    tkern<<<(256 * 80 + 255) / 256, 256, 0, stream>>>(prenet_w1, (float*)(wsu + W1T_U), 256, 80);
    tkern<<<(128 * 256 + 255) / 256, 256, 0, stream>>>(prenet_w2, (float*)(wsu + W2T_U), 128, 256);

    prenet_kern<<<6400, 256, 0, stream>>>(memory, (float*)(wsu + W1T_U), prenet_b1,
                                          (float*)(wsu + W2T_U), prenet_b2,
                                          (float*)(wsu + P2ALL_U));

    {
        float* inpT = (float*)(wsu + P2ALL_U + 819200);
        tkern<<<(128 * 512 + 255) / 256, 256, 0, stream>>>(inp_w, inpT, 128, 512);
        proc_kern<<<4096, 1024, 0, stream>>>(inputs, inpT, (_Float16*)(wsu + PROCF_U));
    }

    decoder_kern<<<64, 1024, 0, stream>>>(inputs, wsu,
                                          att_b_ih, att_b_hh, v_w, v_b,
                                          loc_conv, loc_w, pd_b,
                                          d1_b_ih, d1_b_hh, d2_b_ih, d2_b_hh,
                                          mel_b, stop_w, stop_b, out);
}